// Round 7
// baseline (386.041 us; speedup 1.0000x reference)
//
#include <hip/hip_runtime.h>

#define MDIM 8192
#define NDIM 4096
#define KDIM 4096
#define BM 256
#define BN 256
#define BK 128

typedef int v4i __attribute__((ext_vector_type(4)));
typedef int v16i __attribute__((ext_vector_type(16)));

__device__ __forceinline__ unsigned pack4(int x, int y, int z, int w) {
    return (unsigned)(x & 0xff) | ((unsigned)(y & 0xff) << 8) |
           ((unsigned)(z & 0xff) << 16) | ((unsigned)w << 24);
}

// ---- pass 1: int32 -> packed int8, pre-tiled ---- (unchanged)
// A and B tiles: 256 rows x 128 k, granule-major [kb 0..7][row 0..255],
// granule = 16 B of k for one row == exact MFMA fragment order.
__global__ __launch_bounds__(256) void pack_tiled(const int* __restrict__ x,
                                                  const int* __restrict__ w,
                                                  uint4* __restrict__ xp,
                                                  uint4* __restrict__ wp) {
    __shared__ unsigned lds32[256 * 33];
    const int wg  = blockIdx.x;
    const int tid = threadIdx.x;
    const int kq   = tid & 31;
    const int rsub = tid >> 5;

    const int* src;
    uint4* dst;
    if (wg < 1024) {
        const int mtile = wg >> 5, kiter = wg & 31;
        src = x + (size_t)(mtile * 256) * KDIM + kiter * 128;
        dst = xp + (size_t)(mtile * 32 + kiter) * 2048;
    } else {
        const int ntile = (wg - 1024) >> 5, kiter = wg & 31;
        src = w + (size_t)(ntile * 256) * KDIM + kiter * 128;
        dst = wp + (size_t)(ntile * 32 + kiter) * 2048;
    }
#pragma unroll
    for (int it = 0; it < 32; ++it) {
        const int row = it * 8 + rsub;
        int4 v = *(const int4*)(src + (size_t)row * KDIM + kq * 4);
        lds32[row * 33 + kq] = pack4(v.x, v.y, v.z, v.w);
    }
    __syncthreads();
#pragma unroll
    for (int it = 0; it < 8; ++it) {
        const int g = it * 256 + tid;
        const int kb = g >> 8, row = g & 255;
        const unsigned* p = &lds32[row * 33 + kb * 4];
        uint4 o;
        o.x = p[0]; o.y = p[1]; o.z = p[2]; o.w = p[3];
        dst[g] = o;
    }
}

// ---- pass 2: int8 GEMM, out = x @ W^T ----
// 256x256 tile, 8 waves (2M x 4N), wave tile 128x64, acc[4][2] v16i.
// R7: LDS BYTE-VOLUME fix. R1-R6 all pinned at MfmaUtil 45-51% because
// per-tile LDS service (A 128KB x4-redundant reads + B 64KB x2 reads +
// 64KB DMA writes = 256KB ~ 2280 cyc @112B/cyc) EQUALS the MFMA floor
// (2340 cyc) -- two saturated pipes can't overlap past ~50%. No schedule
// fixes that (R6 anti-phase: null). Fix: B leaves LDS. B fragments are
// register double-buffered ACROSS tiles: B(t+1)'s 8 global_load_dwordx4
// issue at the top of tile t, consumed after the next TOPBAR (~2000 cyc
// cover -- R4's regression was 150-cyc cover, not the B-from-global idea
// itself). LDS traffic drops to 160KB/tile (~1430 cyc), well under MFMA.
//   LDS: A-only 2x32KB double buffer. One vmcnt(0)+barrier per tile
//   (drains A-DMA(t) + B(t) regs, both issued a full tile earlier).
// VGPR budget: acc 128 + af 32 + bfX/bfY 64 + addr ~25 = ~249 <= 256;
// launch_bounds(512,2) forces the fit (falsifier: scratch spill).
__global__ __launch_bounds__(512, 2) void gemm_i8_breg(const char* __restrict__ Ap,
                                                       const char* __restrict__ Bp,
                                                       const _Float16* __restrict__ bias,
                                                       _Float16* __restrict__ out) {
    __shared__ __align__(16) char lds[65536];   // A double buffer only

    const int tid  = threadIdx.x;
    const int lane = tid & 63;
    const int wave = tid >> 6;
    const int wr   = wave >> 2;   // 0..1  (M half)
    const int wcn  = wave & 3;    // 0..3  (N quarter)
    const int l31  = lane & 31;
    const int kg   = lane >> 5;

    // bijective XCD-chunked swizzle: 512 blocks, 8 XCDs, region 4bx x 16by.
    const int lid = blockIdx.y * 16 + blockIdx.x;
    const int xc  = lid & 7, ii = lid >> 3;
    const int bx  = (xc & 3) * 4 + (ii & 3);     // 0..15
    const int by  = (xc >> 2) * 16 + (ii >> 2);  // 0..31
    const int bm0 = by * BM;
    const int bn0 = bx * BN;

    const char* apan = Ap + (size_t)by * (BM * KDIM) + tid * 16;  // A DMA src
    const char* bpan = Bp + (size_t)bx * (BN * KDIM);             // B frag src

    int aoff[4], boffG[2];
#pragma unroll
    for (int mt = 0; mt < 4; ++mt)
        aoff[mt] = (wr * 128 + mt * 32 + l31) * 16 + kg * 4096;
#pragma unroll
    for (int nt = 0; nt < 2; ++nt)
        boffG[nt] = (wcn * 64 + nt * 32 + l31) * 16 + kg * 4096;

    v16i acc[4][2];
#pragma unroll
    for (int mt = 0; mt < 4; ++mt)
#pragma unroll
        for (int nt = 0; nt < 2; ++nt)
#pragma unroll
            for (int i = 0; i < 16; ++i) acc[mt][nt][i] = 0;

    v4i afP[4], afQ[4];          // A-frag ping-pong
    v4i bfX[2][4], bfY[2][4];    // B-frag tile-level double buffer

    auto stageA = [&](int nb) {  // 4 gload_lds: 32 KB A tile
#pragma unroll
        for (int c2 = 0; c2 < 4; ++c2)
            __builtin_amdgcn_global_load_lds(
                (__attribute__((address_space(1))) const void*)(apan + c2 * 8192),
                (__attribute__((address_space(3))) void*)(lds + nb + c2 * 8192 + tid * 16),
                16, 0, 0);
    };
    auto loadB = [&](v4i (&d)[2][4]) {  // 8 global_load_dwordx4 (512B segs)
#pragma unroll
        for (int nt = 0; nt < 2; ++nt)
#pragma unroll
            for (int ks = 0; ks < 4; ++ks)
                d[nt][ks] = *(const v4i*)(bpan + boffG[nt] + ks * 8192);
    };
    auto readA = [&](v4i (&d)[4], int base, int ks) {  // 4 ds_read_b128
#pragma unroll
        for (int mt = 0; mt < 4; ++mt)
            d[mt] = *(const v4i*)(lds + base + ks * 8192 + aoff[mt]);
    };
    auto cl = [&](const v4i (&a)[4], const v4i (&b)[2][4], int k) {  // 8 MFMA
        __builtin_amdgcn_s_setprio(1);
#pragma unroll
        for (int mt = 0; mt < 4; ++mt)
#pragma unroll
            for (int nt = 0; nt < 2; ++nt)
                acc[mt][nt] = __builtin_amdgcn_mfma_i32_32x32x32_i8(
                    a[mt], b[nt][k], acc[mt][nt], 0, 0, 0);
        __builtin_amdgcn_s_setprio(0);
    };

#define SB0 __builtin_amdgcn_sched_barrier(0)
#define TOPBAR do { asm volatile("s_waitcnt vmcnt(0)" ::: "memory"); \
                    __builtin_amdgcn_s_barrier(); } while (0)

    // body of tile t: compute from (cur LDS buf, bf); prefetch tile t+1
    // (A-DMA -> nxt buf, B -> bfn). One barrier, at the top.
    auto body = [&](int cur, const v4i (&bf)[2][4], int nxt, v4i (&bfn)[2][4],
                    bool stg) {
        TOPBAR; SB0;                 // drains A-DMA(t) + B(t), issued in t-1
        readA(afP, cur, 0);          // A ks0 (the one exposed-latency read)
        readA(afQ, cur, 1);          // A ks1
        SB0;
        if (stg) {
            stageA(nxt);             // A(t+1) -> other LDS buf
            loadB(bfn);              // B(t+1) -> other reg set
            apan += BM * BK;
            bpan += BN * BK;
        }
        SB0;
        cl(afP, bf, 0); SB0;         // ks0
        readA(afP, cur, 2); SB0;     // A ks2 under ks0's MFMA
        cl(afQ, bf, 1); SB0;         // ks1
        readA(afQ, cur, 3); SB0;     // A ks3 under ks1's MFMA
        cl(afP, bf, 2); SB0;         // ks2
        cl(afQ, bf, 3);              // ks3
    };

    // ---- prologue: stage tile 0 ----
    stageA(0);
    loadB(bfX);
    apan += BM * BK;
    bpan += BN * BK;

    // tile 0 (one-time full-latency drain happens at its TOPBAR)
    body(0, bfX, 32768, bfY, true);

#pragma unroll 1
    for (int p = 0; p < 15; ++p) {   // tiles 2p+1 (buf1/bfY), 2p+2 (buf0/bfX)
        body(32768, bfY, 0, bfX, true);
        body(0, bfX, 32768, bfY, true);
    }
    body(32768, bfY, 0, bfX, false); // tile 31

#undef SB0
#undef TOPBAR

    // epilogue: int32 -> fp16 (exact; overflow -> inf matches ref), + bias.
    // C/D layout: col=lane&31, row=(reg&3)+8*(reg>>2)+4*(lane>>5)
    const _Float16 bv0 = bias[bn0 + wcn * 64 + l31];
    const _Float16 bv1 = bias[bn0 + wcn * 64 + 32 + l31];
#pragma unroll
    for (int mt = 0; mt < 4; ++mt) {
#pragma unroll
        for (int nt = 0; nt < 2; ++nt) {
            const int gcol = bn0 + wcn * 64 + nt * 32 + l31;
            const _Float16 bb = nt ? bv1 : bv0;
#pragma unroll
            for (int r = 0; r < 16; ++r) {
                const int rit  = (r & 3) + 8 * (r >> 2) + 4 * kg;
                const int grow = bm0 + wr * 128 + mt * 32 + rit;
                _Float16 h = (_Float16)(float)acc[mt][nt][r] + bb;
                out[(size_t)grow * NDIM + gcol] = h;
            }
        }
    }
}

// ---- fallback (no workspace): non-pipelined, packs in regs ---- (unchanged)
__global__ __launch_bounds__(256, 2) void gemm_i8_fb(const int* __restrict__ A32,
                                                     const int* __restrict__ B32,
                                                     const _Float16* __restrict__ bias,
                                                     _Float16* __restrict__ out) {
    __shared__ char lds[32768];
    const int tid  = threadIdx.x;
    const int lane = tid & 63;
    const int wave = tid >> 6;
    const int bm0 = blockIdx.y * 256;
    const int bn0 = blockIdx.x * 128;
    const int wr  = wave >> 1;
    const int wc  = wave & 1;
    const int l31 = lane & 31;
    const int kg  = lane >> 5;

    int abase[4];
#pragma unroll
    for (int mt = 0; mt < 4; ++mt)
        abase[mt] = kg * 4096 + (wr * 128 + mt * 32 + l31) * 16;

    v16i acc[4][2];
#pragma unroll
    for (int mt = 0; mt < 4; ++mt)
#pragma unroll
        for (int nt = 0; nt < 2; ++nt)
#pragma unroll
            for (int i = 0; i < 16; ++i) acc[mt][nt][i] = 0;

    int aoffs[8];
#pragma unroll
    for (int r = 0; r < 8; ++r) {
        const int c = r * 4 + wave;
        aoffs[r] = (bm0 + (c & 3) * 64 + lane) * KDIM + (c >> 2) * 16;
    }
    for (int k0 = 0; k0 < KDIM; k0 += 128) {
        v4i bfx[2][4];
#pragma unroll
        for (int r = 0; r < 8; ++r) {
            const int c = r * 4 + wave;
            const int4* s = (const int4*)(A32 + (size_t)aoffs[r]);
            int4 v0 = s[0], v1 = s[1], v2 = s[2], v3 = s[3];
            uint4 pk;
            pk.x = pack4(v0.x, v0.y, v0.z, v0.w);
            pk.y = pack4(v1.x, v1.y, v1.z, v1.w);
            pk.z = pack4(v2.x, v2.y, v2.z, v2.w);
            pk.w = pack4(v3.x, v3.y, v3.z, v3.w);
            *(uint4*)(lds + c * 1024 + lane * 16) = pk;
            aoffs[r] += 128;
        }
#pragma unroll
        for (int nt = 0; nt < 2; ++nt)
#pragma unroll
            for (int ks = 0; ks < 4; ++ks) {
                const int* s = B32 + (size_t)(bn0 + wc * 64 + nt * 32 + l31) * KDIM
                               + k0 + (2 * ks + kg) * 16;
                int4 v0 = ((const int4*)s)[0], v1 = ((const int4*)s)[1];
                int4 v2 = ((const int4*)s)[2], v3 = ((const int4*)s)[3];
                bfx[nt][ks][0] = (int)pack4(v0.x, v0.y, v0.z, v0.w);
                bfx[nt][ks][1] = (int)pack4(v1.x, v1.y, v1.z, v1.w);
                bfx[nt][ks][2] = (int)pack4(v2.x, v2.y, v2.z, v2.w);
                bfx[nt][ks][3] = (int)pack4(v3.x, v3.y, v3.z, v3.w);
            }
        __syncthreads();
#pragma unroll
        for (int ks = 0; ks < 4; ++ks) {
            v4i afr[4];
#pragma unroll
            for (int mt = 0; mt < 4; ++mt)
                afr[mt] = *(const v4i*)(lds + abase[mt] + ks * 8192);
#pragma unroll
            for (int mt = 0; mt < 4; ++mt)
#pragma unroll
                for (int nt = 0; nt < 2; ++nt)
                    acc[mt][nt] = __builtin_amdgcn_mfma_i32_32x32x32_i8(
                        afr[mt], bfx[nt][ks], acc[mt][nt], 0, 0, 0);
        }
        __syncthreads();
    }

    const _Float16 bv0 = bias[bn0 + wc * 64 + l31];
    const _Float16 bv1 = bias[bn0 + wc * 64 + 32 + l31];
#pragma unroll
    for (int mt = 0; mt < 4; ++mt) {
#pragma unroll
        for (int nt = 0; nt < 2; ++nt) {
            const int gcol = bn0 + wc * 64 + nt * 32 + l31;
            const _Float16 bb = nt ? bv1 : bv0;
#pragma unroll
            for (int r = 0; r < 16; ++r) {
                const int rit  = (r & 3) + 8 * (r >> 2) + 4 * kg;
                const int grow = bm0 + wr * 128 + mt * 32 + rit;
                _Float16 h = (_Float16)(float)acc[mt][nt][r] + bb;
                out[(size_t)grow * NDIM + gcol] = h;
            }
        }
    }
}

extern "C" void kernel_launch(void* const* d_in, const int* in_sizes, int n_in,
                              void* d_out, int out_size, void* d_ws, size_t ws_size,
                              hipStream_t stream) {
    const int* x = (const int*)d_in[0];
    const int* w = (const int*)d_in[1];
    const _Float16* bias = (const _Float16*)d_in[2];
    _Float16* out = (_Float16*)d_out;

    const size_t xbytes = (size_t)MDIM * KDIM;  // packed int8 bytes
    const size_t wbytes = (size_t)NDIM * KDIM;

    if (ws_size >= xbytes + wbytes) {
        char* xp = (char*)d_ws;
        char* wp = xp + xbytes;
        pack_tiled<<<1536, 256, 0, stream>>>(x, w, (uint4*)xp, (uint4*)wp);
        gemm_i8_breg<<<dim3(NDIM / BN, MDIM / BM), 512, 0, stream>>>(
            (const char*)xp, (const char*)wp, bias, out);
    } else {
        gemm_i8_fb<<<dim3(NDIM / 128, MDIM / 256), 256, 0, stream>>>(
            x, w, bias, out);
    }
}